// Round 4
// baseline (559.863 us; speedup 1.0000x reference)
//
#include <hip/hip_runtime.h>
#include <hip/hip_bf16.h>
#include <stdint.h>

typedef unsigned short ushort_t;
typedef __attribute__((ext_vector_type(8))) short short8;
typedef __attribute__((ext_vector_type(4))) float floatx4;

__device__ __forceinline__ ushort_t f2b(float f) {
    unsigned u = __float_as_uint(f);
    unsigned r = (u + 0x7FFFu + ((u >> 16) & 1u)) >> 16;
    return (ushort_t)r;
}
__device__ __forceinline__ float b2f(ushort_t h) {
    return __uint_as_float(((unsigned)h) << 16);
}
__device__ __forceinline__ float elu1(float f) {
    return (f > 0.f) ? (f + 1.f) : __expf(f);
}

#define GLDS16(srcp, dstp)                                                          \
    __builtin_amdgcn_global_load_lds(                                               \
        (const __attribute__((address_space(1))) unsigned int*)(srcp),              \
        (__attribute__((address_space(3))) unsigned int*)(dstp), 16, 0, 0)

// ---------------- conversion kernels ----------------

__global__ void conv_bf16(const float* __restrict__ in, ushort_t* __restrict__ out, int n8) {
    for (int i = blockIdx.x * blockDim.x + threadIdx.x; i < n8; i += gridDim.x * blockDim.x) {
        const float4 f0 = *(const float4*)&in[(size_t)i * 8];
        const float4 f1 = *(const float4*)&in[(size_t)i * 8 + 4];
        ushort4 o0, o1;
        o0.x = f2b(f0.x); o0.y = f2b(f0.y); o0.z = f2b(f0.z); o0.w = f2b(f0.w);
        o1.x = f2b(f1.x); o1.y = f2b(f1.y); o1.z = f2b(f1.z); o1.w = f2b(f1.w);
        *(ushort4*)&out[(size_t)i * 8]     = o0;
        *(ushort4*)&out[(size_t)i * 8 + 4] = o1;
    }
}

__global__ void transpose_conv(const float* __restrict__ in, ushort_t* __restrict__ out,
                               int R, int C) {
    __shared__ float tile[32][33];
    int c0 = blockIdx.x * 32, r0 = blockIdx.y * 32;
    int tx = threadIdx.x, ty = threadIdx.y;
#pragma unroll
    for (int k = 0; k < 4; ++k) {
        int a = ty * 4 + k;
        tile[a][tx] = in[(size_t)(r0 + a) * C + c0 + tx];
    }
    __syncthreads();
#pragma unroll
    for (int k = 0; k < 4; ++k) {
        int a = ty * 4 + k;
        out[(size_t)(c0 + a) * R + r0 + tx] = f2b(tile[tx][a]);
    }
}

__global__ void zero_f32(float* __restrict__ p, int n) {
    int i = blockIdx.x * blockDim.x + threadIdx.x;
    if (i < n) p[i] = 0.f;
}

// ---------------- 256x256 8-phase GEMM: C = A @ Bt^T, K = 1024 fixed ----------------
// Swapped-operand MFMA: lane holds 4 consecutive n-columns -> packed stores.
// MODE 0: bf16 out, linear [M][Nt], + bias (no activation)
// MODE 1: fp32 out, linear [M][Nt], + bias
template<int MODE>
__global__ __launch_bounds__(512, 2) void gemm256(
    const ushort_t* __restrict__ A, const ushort_t* __restrict__ Bt,
    const float* __restrict__ bias,
    ushort_t* __restrict__ out_u16, float* __restrict__ out_f32,
    int Nt, int nbx)
{
    extern __shared__ ushort_t lds[];   // 65536 elements = 128 KiB
    constexpr int KK = 1024;

    const int tid  = threadIdx.x;
    const int wave = tid >> 6;
    const int lane = tid & 63;
    const int wm_i = wave >> 2;
    const int wn_i = wave & 3;
    const int fr   = lane & 15;
    const int fq   = lane >> 4;

    // XCD-bijective block swizzle (grid % 8 == 0)
    const int nwg = (int)gridDim.x;
    const int bid = (int)blockIdx.x;
    const int swz = (bid & 7) * (nwg >> 3) + (bid >> 3);
    const int bx = swz % nbx, by = swz / nbx;
    const int m0 = by * 256, n0 = bx * 256;

    // staging per-thread constants
    const int trow = tid >> 3;
    const int csw  = ((tid & 7) ^ (trow & 7)) << 3;
    const int tcolB = ((tid >> 8) << 6) + (trow & 31);

    const ushort_t* sa = A  + (size_t)(m0 + trow)  * KK + csw;
    const ushort_t* sb = Bt + (size_t)(n0 + tcolB) * KK + csw;

    const int dstA = wave * 512;
    const int dstB = 16384 + wave * 512;

    const int sw0 = (fq ^ (fr & 7)) << 3;
    const int sw1 = sw0 ^ 32;
    const int abase = (wm_i * 64 + fr) * 64;
    const int bbase = (wn_i * 32 + fr) * 64;
    int loA0[2][2], loA1[2][2], loB0[2][2], loB1[2][2];
#pragma unroll
    for (int bf = 0; bf < 2; ++bf)
#pragma unroll
        for (int q = 0; q < 2; ++q) {
            loA0[bf][q] = bf * 32768 + q * 8192 + abase + sw0;
            loA1[bf][q] = bf * 32768 + q * 8192 + abase + sw1;
            loB0[bf][q] = bf * 32768 + 16384 + q * 8192 + bbase + sw0;
            loB1[bf][q] = bf * 32768 + 16384 + q * 8192 + bbase + sw1;
        }

    floatx4 acc[8][4];
    const floatx4 z4 = {0.f, 0.f, 0.f, 0.f};
#pragma unroll
    for (int i = 0; i < 8; ++i)
#pragma unroll
        for (int j = 0; j < 4; ++j) acc[i][j] = z4;

    short8 a[4][2], b[2][2];

    auto stageA = [&](int buf, int h, int ko) {
        ushort_t* d = lds + buf * 32768 + h * 8192 + dstA;
        GLDS16(sa + h * (64 * KK) + ko, d);
        GLDS16(sa + h * (64 * KK) + 128 * KK + ko, d + 4096);
    };
    auto stageB = [&](int buf, int h, int ko) {
        ushort_t* d = lds + buf * 32768 + h * 8192 + dstB;
        GLDS16(sb + h * (32 * KK) + ko, d);
        GLDS16(sb + h * (32 * KK) + 128 * KK + ko, d + 4096);
    };
    auto loadA = [&](int buf, int qr) {
        const int o0 = loA0[buf][qr], o1 = loA1[buf][qr];
#pragma unroll
        for (int i = 0; i < 4; ++i) {
            a[i][0] = *(const short8*)(lds + o0 + i * 1024);
            a[i][1] = *(const short8*)(lds + o1 + i * 1024);
        }
    };
    auto loadB = [&](int buf, int qc) {
        const int o0 = loB0[buf][qc], o1 = loB1[buf][qc];
#pragma unroll
        for (int j = 0; j < 2; ++j) {
            b[j][0] = *(const short8*)(lds + o0 + j * 1024);
            b[j][1] = *(const short8*)(lds + o1 + j * 1024);
        }
    };
    // swapped operands: D^T -> lane fq*4+r indexes n (cols), fr indexes m (rows)
    auto mma = [&](int qr, int qc) {
#pragma unroll
        for (int i = 0; i < 4; ++i)
#pragma unroll
            for (int j = 0; j < 2; ++j) {
                acc[qr * 4 + i][qc * 2 + j] =
                    __builtin_amdgcn_mfma_f32_16x16x32_bf16(b[j][0], a[i][0], acc[qr * 4 + i][qc * 2 + j], 0, 0, 0);
                acc[qr * 4 + i][qc * 2 + j] =
                    __builtin_amdgcn_mfma_f32_16x16x32_bf16(b[j][1], a[i][1], acc[qr * 4 + i][qc * 2 + j], 0, 0, 0);
            }
    };

#define PRIO1() __builtin_amdgcn_s_setprio(1)
#define BOUT()  __builtin_amdgcn_s_setprio(0); __builtin_amdgcn_s_barrier()
#define VM6()   asm volatile("s_waitcnt vmcnt(6)" ::: "memory")
#define VM0()   asm volatile("s_waitcnt vmcnt(0)" ::: "memory")

    // prologue: stream order per tile = [A0, B1, A1, B0]
    stageA(0, 0, 0);
    stageB(0, 1, 0);
    stageA(0, 1, 0);
    stageB(0, 0, 0);
    stageA(1, 0, 64);
    stageB(1, 1, 64);
    stageA(1, 1, 64);
    VM6();
    __builtin_amdgcn_s_barrier();

    int ko = 0;
    for (int pr = 0; pr < 7; ++pr, ko += 128) {
        // ---- tile t0 (buf0) ----
        loadA(0, 0); loadB(0, 0);
        stageB(1, 0, ko + 64);
        PRIO1(); mma(0, 0); BOUT();

        loadB(0, 1);
        stageA(0, 0, ko + 128);
        PRIO1(); mma(0, 1); BOUT();

        loadA(0, 1);
        stageB(0, 1, ko + 128);
        PRIO1(); mma(1, 1); BOUT();

        loadB(0, 0);
        stageA(0, 1, ko + 128);
        PRIO1(); mma(1, 0); __builtin_amdgcn_s_setprio(0); VM6();
        __builtin_amdgcn_s_barrier();

        // ---- tile t0+1 (buf1) ----
        loadA(1, 0); loadB(1, 0);
        stageB(0, 0, ko + 128);
        PRIO1(); mma(0, 0); BOUT();

        loadB(1, 1);
        stageA(1, 0, ko + 192);
        PRIO1(); mma(0, 1); BOUT();

        loadA(1, 1);
        stageB(1, 1, ko + 192);
        PRIO1(); mma(1, 1); BOUT();

        loadB(1, 0);
        stageA(1, 1, ko + 192);
        PRIO1(); mma(1, 0); __builtin_amdgcn_s_setprio(0); VM6();
        __builtin_amdgcn_s_barrier();
    }

    // peeled last iteration: tiles 14 (buf0), 15 (buf1); ko == 896
    loadA(0, 0); loadB(0, 0);
    stageB(1, 0, 960);
    PRIO1(); mma(0, 0); BOUT();

    loadB(0, 1);
    PRIO1(); mma(0, 1); BOUT();

    loadA(0, 1);
    PRIO1(); mma(1, 1); BOUT();

    loadB(0, 0);
    PRIO1(); mma(1, 0); __builtin_amdgcn_s_setprio(0); VM0();
    __builtin_amdgcn_s_barrier();

    loadA(1, 0); loadB(1, 0);
    PRIO1(); mma(0, 0); BOUT();

    loadB(1, 1);
    PRIO1(); mma(0, 1); BOUT();

    loadA(1, 1);
    PRIO1(); mma(1, 1); BOUT();

    loadB(1, 0);
    PRIO1(); mma(1, 0);
    __builtin_amdgcn_s_setprio(0);

#undef PRIO1
#undef BOUT
#undef VM6
#undef VM0

    // epilogue (swapped layout):
    //   m = m0 + wm_i*128 + (ri>>2)*64 + (ri&3)*16 + fr
    //   n = n0 + wn_i*64 + (cj>>1)*32 + (cj&1)*16 + fq*4 + r
    float4 bv[4];
#pragma unroll
    for (int cj = 0; cj < 4; ++cj) {
        const int nb = n0 + wn_i * 64 + (cj >> 1) * 32 + (cj & 1) * 16 + fq * 4;
        bv[cj] = *(const float4*)&bias[nb];
    }
#pragma unroll
    for (int ri = 0; ri < 8; ++ri) {
        const int m = m0 + wm_i * 128 + (ri >> 2) * 64 + (ri & 3) * 16 + fr;
#pragma unroll
        for (int cj = 0; cj < 4; ++cj) {
            const int nb = n0 + wn_i * 64 + (cj >> 1) * 32 + (cj & 1) * 16 + fq * 4;
            if (MODE == 0) {
                ushort4 o;
                o.x = f2b(acc[ri][cj][0] + bv[cj].x);
                o.y = f2b(acc[ri][cj][1] + bv[cj].y);
                o.z = f2b(acc[ri][cj][2] + bv[cj].z);
                o.w = f2b(acc[ri][cj][3] + bv[cj].w);
                *(ushort4*)&out_u16[(size_t)m * Nt + nb] = o;
            } else {
                float4 o;
                o.x = acc[ri][cj][0] + bv[cj].x;
                o.y = acc[ri][cj][1] + bv[cj].y;
                o.z = acc[ri][cj][2] + bv[cj].z;
                o.w = acc[ri][cj][3] + bv[cj].w;
                *(float4*)&out_f32[(size_t)m * Nt + nb] = o;
            }
        }
    }
}

// ---------------- kv = elu1(k)^T v  (+ ksum) per (b,h) ----------------
// qkvb: [32768][3072] bf16 linear. k at col 1024+h*64, v at col 2048+h*64.
__global__ __launch_bounds__(256) void kv_kernel(
    const ushort_t* __restrict__ qkvb,
    float* __restrict__ kv, float* __restrict__ ksum)
{
    __shared__ ushort_t ks[64 * 64] __attribute__((aligned(16)));
    __shared__ ushort_t vs[64 * 64] __attribute__((aligned(16)));

    const int bh = blockIdx.y, chunk = blockIdx.x, t = threadIdx.x;
    const int b = bh >> 4, h = bh & 15;
    const int d0 = (t >> 4) * 4, e0 = (t & 15) * 4;
    const bool do_ksum = (t & 15) == 0;

    const int sr = t >> 2;            // stage row 0..63
    const int sc = (t & 3) * 16;      // stage col 0,16,32,48

    float acc[4][4];
#pragma unroll
    for (int i = 0; i < 4; ++i)
#pragma unroll
        for (int j = 0; j < 4; ++j) acc[i][j] = 0.f;
    float kacc[4] = {0.f, 0.f, 0.f, 0.f};

    for (int sub = 0; sub < 8; ++sub) {
        const int nb = chunk * 512 + sub * 64;
        __syncthreads();
        {
            const ushort_t* row = qkvb + ((size_t)b * 8192 + nb + sr) * 3072 + h * 64 + sc;
            // k with elu1
            short8 k0 = *(const short8*)(row + 1024);
            short8 k1 = *(const short8*)(row + 1024 + 8);
            short8 ko0, ko1;
#pragma unroll
            for (int i = 0; i < 8; ++i) {
                ko0[i] = (short)f2b(elu1(b2f((ushort_t)k0[i])));
                ko1[i] = (short)f2b(elu1(b2f((ushort_t)k1[i])));
            }
            *(short8*)&ks[sr * 64 + sc]     = ko0;
            *(short8*)&ks[sr * 64 + sc + 8] = ko1;
            // v straight copy
            *(short8*)&vs[sr * 64 + sc]     = *(const short8*)(row + 2048);
            *(short8*)&vs[sr * 64 + sc + 8] = *(const short8*)(row + 2048 + 8);
        }
        __syncthreads();
        for (int n = 0; n < 64; ++n) {
            ushort4 kd = *(const ushort4*)&ks[n * 64 + d0];
            ushort4 ve = *(const ushort4*)&vs[n * 64 + e0];
            float kf[4] = {b2f(kd.x), b2f(kd.y), b2f(kd.z), b2f(kd.w)};
            float vf[4] = {b2f(ve.x), b2f(ve.y), b2f(ve.z), b2f(ve.w)};
#pragma unroll
            for (int i = 0; i < 4; ++i) {
#pragma unroll
                for (int j = 0; j < 4; ++j) acc[i][j] += kf[i] * vf[j];
            }
            if (do_ksum) {
#pragma unroll
                for (int i = 0; i < 4; ++i) kacc[i] += kf[i];
            }
        }
    }
#pragma unroll
    for (int i = 0; i < 4; ++i) {
        if (do_ksum) atomicAdd(&ksum[bh * 64 + d0 + i], kacc[i]);
#pragma unroll
        for (int j = 0; j < 4; ++j)
            atomicAdd(&kv[((size_t)bh * 64 + d0 + i) * 64 + e0 + j], acc[i][j]);
    }
}

// ---------------- out = (elu1(q) @ kv) * z, repack to [B][N][C] bf16 ----------------
__global__ __launch_bounds__(256) void out_kernel(
    const ushort_t* __restrict__ qkvb, const float* __restrict__ kv,
    const float* __restrict__ ksum, ushort_t* __restrict__ obuf)
{
    __shared__ float kvs[4096];
    __shared__ float ksums[64];
    __shared__ float qs[16][65];

    const int bh = blockIdx.y, chunk = blockIdx.x, t = threadIdx.x;
    const int b = bh >> 4, h = bh & 15;
    const int myrow = t >> 4, e0 = (t & 15) * 4;

#pragma unroll
    for (int i = 0; i < 4; ++i) {
        int idx = (i * 256 + t) * 4;
        *(float4*)&kvs[idx] = *(const float4*)&kv[(size_t)bh * 4096 + idx];
    }
    if (t < 64) ksums[t] = ksum[bh * 64 + t];

    for (int pass = 0; pass < 8; ++pass) {
        const int n = chunk * 128 + pass * 16 + myrow;
        __syncthreads();
        {
            int col = (t & 15) * 4;
            ushort4 qv4 = *(const ushort4*)&qkvb[((size_t)b * 8192 + n) * 3072 + h * 64 + col];
            qs[myrow][col + 0] = elu1(b2f(qv4.x));
            qs[myrow][col + 1] = elu1(b2f(qv4.y));
            qs[myrow][col + 2] = elu1(b2f(qv4.z));
            qs[myrow][col + 3] = elu1(b2f(qv4.w));
        }
        __syncthreads();
        float a0 = 0.f, a1 = 0.f, a2 = 0.f, a3 = 0.f, z = 0.f;
        for (int d = 0; d < 64; ++d) {
            const float qv = qs[myrow][d];
            const float4 kvv = *(const float4*)&kvs[d * 64 + e0];
            a0 += qv * kvv.x; a1 += qv * kvv.y; a2 += qv * kvv.z; a3 += qv * kvv.w;
            z += qv * ksums[d];
        }
        const float zi = 1.f / (z + 1e-8f);
        ushort4 o;
        o.x = f2b(a0 * zi); o.y = f2b(a1 * zi); o.z = f2b(a2 * zi); o.w = f2b(a3 * zi);
        *(ushort4*)&obuf[((size_t)b * 8192 + n) * 1024 + h * 64 + e0] = o;
    }
}

// ---------------- launch ----------------

extern "C" void kernel_launch(void* const* d_in, const int* in_sizes, int n_in,
                              void* d_out, int out_size, void* d_ws, size_t ws_size,
                              hipStream_t stream) {
    const float* x      = (const float*)d_in[0];
    const float* w_qkv  = (const float*)d_in[1];
    const float* b_qkv  = (const float*)d_in[2];
    const float* w_proj = (const float*)d_in[3];
    const float* b_proj = (const float*)d_in[4];
    float* out = (float*)d_out;

    const size_t XE = (size_t)32768 * 1024;

    char* ws = (char*)d_ws;
    ushort_t* xb   = (ushort_t*)ws;  ws += XE * 2;
    ushort_t* wqT  = (ushort_t*)ws;  ws += (size_t)3072 * 1024 * 2;
    ushort_t* wpT  = (ushort_t*)ws;  ws += (size_t)1024 * 1024 * 2;
    ushort_t* qkvb = (ushort_t*)ws;  ws += 3 * XE * 2;   // [32768][3072] linear
    ushort_t* ob   = (ushort_t*)ws;  ws += XE * 2;       // [32768][1024]
    float*    kv   = (float*)ws;     ws += (size_t)64 * 64 * 64 * 4;
    float*    ksum = (float*)ws;     ws += (size_t)64 * 64 * 4;

    (void)hipFuncSetAttribute(reinterpret_cast<const void*>(gemm256<0>),
                              hipFuncAttributeMaxDynamicSharedMemorySize, 131072);
    (void)hipFuncSetAttribute(reinterpret_cast<const void*>(gemm256<1>),
                              hipFuncAttributeMaxDynamicSharedMemorySize, 131072);

    zero_f32<<<dim3((64 * 64 * 64 + 64 * 64 + 255) / 256), dim3(256), 0, stream>>>(kv, 64 * 64 * 64 + 64 * 64);
    conv_bf16<<<dim3(2048), dim3(256), 0, stream>>>(x, xb, (int)(XE / 8));
    transpose_conv<<<dim3(96, 32), dim3(32, 8), 0, stream>>>(w_qkv, wqT, 1024, 3072);
    transpose_conv<<<dim3(32, 32), dim3(32, 8), 0, stream>>>(w_proj, wpT, 1024, 1024);

    // qkv: M=32768, Nt=3072 -> 12*128 = 1536 blocks
    gemm256<0><<<dim3(1536), dim3(512), 131072, stream>>>(xb, wqT, b_qkv, qkvb, nullptr, 3072, 12);

    kv_kernel<<<dim3(16, 64), dim3(256), 0, stream>>>(qkvb, kv, ksum);
    out_kernel<<<dim3(64, 64), dim3(256), 0, stream>>>(qkvb, kv, ksum, ob);

    // proj: M=32768, Nt=1024 -> 4*128 = 512 blocks
    gemm256<1><<<dim3(512), dim3(512), 131072, stream>>>(ob, wpT, b_proj, nullptr, out, 1024, 4);
}

// Round 5
// 490.305 us; speedup vs baseline: 1.1419x; 1.1419x over previous
//
#include <hip/hip_runtime.h>
#include <hip/hip_bf16.h>
#include <stdint.h>

typedef unsigned short ushort_t;
typedef __attribute__((ext_vector_type(8))) short short8;
typedef __attribute__((ext_vector_type(4))) float floatx4;

__device__ __forceinline__ ushort_t f2b(float f) {
    unsigned u = __float_as_uint(f);
    unsigned r = (u + 0x7FFFu + ((u >> 16) & 1u)) >> 16;
    return (ushort_t)r;
}
__device__ __forceinline__ float b2f(ushort_t h) {
    return __uint_as_float(((unsigned)h) << 16);
}
__device__ __forceinline__ float elu1(float f) {
    return (f > 0.f) ? (f + 1.f) : __expf(f);
}

#define GLDS16(srcp, dstp)                                                          \
    __builtin_amdgcn_global_load_lds(                                               \
        (const __attribute__((address_space(1))) unsigned int*)(srcp),              \
        (__attribute__((address_space(3))) unsigned int*)(dstp), 16, 0, 0)

// ---------------- conversion kernels ----------------

__global__ void conv_bf16(const float* __restrict__ in, ushort_t* __restrict__ out, int n8) {
    for (int i = blockIdx.x * blockDim.x + threadIdx.x; i < n8; i += gridDim.x * blockDim.x) {
        const float4 f0 = *(const float4*)&in[(size_t)i * 8];
        const float4 f1 = *(const float4*)&in[(size_t)i * 8 + 4];
        ushort4 o0, o1;
        o0.x = f2b(f0.x); o0.y = f2b(f0.y); o0.z = f2b(f0.z); o0.w = f2b(f0.w);
        o1.x = f2b(f1.x); o1.y = f2b(f1.y); o1.z = f2b(f1.z); o1.w = f2b(f1.w);
        *(ushort4*)&out[(size_t)i * 8]     = o0;
        *(ushort4*)&out[(size_t)i * 8 + 4] = o1;
    }
}

__global__ void transpose_conv(const float* __restrict__ in, ushort_t* __restrict__ out,
                               int R, int C) {
    __shared__ float tile[32][33];
    int c0 = blockIdx.x * 32, r0 = blockIdx.y * 32;
    int tx = threadIdx.x, ty = threadIdx.y;
#pragma unroll
    for (int k = 0; k < 4; ++k) {
        int a = ty * 4 + k;
        tile[a][tx] = in[(size_t)(r0 + a) * C + c0 + tx];
    }
    __syncthreads();
#pragma unroll
    for (int k = 0; k < 4; ++k) {
        int a = ty * 4 + k;
        out[(size_t)(c0 + a) * R + r0 + tx] = f2b(tile[tx][a]);
    }
}

__global__ void zero_f32(float* __restrict__ p, int n) {
    int i = blockIdx.x * blockDim.x + threadIdx.x;
    if (i < n) p[i] = 0.f;
}

// ---------------- 256x256 8-phase GEMM: C = A @ Bt^T, K = 1024 fixed ----------------
// Swapped-operand MFMA: lane holds 4 consecutive n-columns -> packed stores.
// MODE 0: qkv epilogue: bias + elu+1 on q,k; packed ushort4 scatter to [3][bh][8192][64]
// MODE 1: proj epilogue: bias; fp32 linear [M][Nt]
template<int MODE>
__global__ __launch_bounds__(512, 2) void gemm256(
    const ushort_t* __restrict__ A, const ushort_t* __restrict__ Bt,
    const float* __restrict__ bias,
    ushort_t* __restrict__ out_u16, float* __restrict__ out_f32,
    int Nt, int nbx)
{
    extern __shared__ ushort_t lds[];   // 65536 elements = 128 KiB
    constexpr int KK = 1024;

    const int tid  = threadIdx.x;
    const int wave = tid >> 6;
    const int lane = tid & 63;
    const int wm_i = wave >> 2;
    const int wn_i = wave & 3;
    const int fr   = lane & 15;
    const int fq   = lane >> 4;

    // XCD-bijective block swizzle (grid % 8 == 0)
    const int nwg = (int)gridDim.x;
    const int bid = (int)blockIdx.x;
    const int swz = (bid & 7) * (nwg >> 3) + (bid >> 3);
    const int bx = swz % nbx, by = swz / nbx;
    const int m0 = by * 256, n0 = bx * 256;

    // staging per-thread constants
    const int trow = tid >> 3;
    const int csw  = ((tid & 7) ^ (trow & 7)) << 3;
    const int tcolB = ((tid >> 8) << 6) + (trow & 31);

    const ushort_t* sa = A  + (size_t)(m0 + trow)  * KK + csw;
    const ushort_t* sb = Bt + (size_t)(n0 + tcolB) * KK + csw;

    const int dstA = wave * 512;
    const int dstB = 16384 + wave * 512;

    const int sw0 = (fq ^ (fr & 7)) << 3;
    const int sw1 = sw0 ^ 32;
    const int abase = (wm_i * 64 + fr) * 64;
    const int bbase = (wn_i * 32 + fr) * 64;
    int loA0[2][2], loA1[2][2], loB0[2][2], loB1[2][2];
#pragma unroll
    for (int bf = 0; bf < 2; ++bf)
#pragma unroll
        for (int q = 0; q < 2; ++q) {
            loA0[bf][q] = bf * 32768 + q * 8192 + abase + sw0;
            loA1[bf][q] = bf * 32768 + q * 8192 + abase + sw1;
            loB0[bf][q] = bf * 32768 + 16384 + q * 8192 + bbase + sw0;
            loB1[bf][q] = bf * 32768 + 16384 + q * 8192 + bbase + sw1;
        }

    floatx4 acc[8][4];
    const floatx4 z4 = {0.f, 0.f, 0.f, 0.f};
#pragma unroll
    for (int i = 0; i < 8; ++i)
#pragma unroll
        for (int j = 0; j < 4; ++j) acc[i][j] = z4;

    short8 a[4][2], b[2][2];

    auto stageA = [&](int buf, int h, int ko) {
        ushort_t* d = lds + buf * 32768 + h * 8192 + dstA;
        GLDS16(sa + h * (64 * KK) + ko, d);
        GLDS16(sa + h * (64 * KK) + 128 * KK + ko, d + 4096);
    };
    auto stageB = [&](int buf, int h, int ko) {
        ushort_t* d = lds + buf * 32768 + h * 8192 + dstB;
        GLDS16(sb + h * (32 * KK) + ko, d);
        GLDS16(sb + h * (32 * KK) + 128 * KK + ko, d + 4096);
    };
    auto loadA = [&](int buf, int qr) {
        const int o0 = loA0[buf][qr], o1 = loA1[buf][qr];
#pragma unroll
        for (int i = 0; i < 4; ++i) {
            a[i][0] = *(const short8*)(lds + o0 + i * 1024);
            a[i][1] = *(const short8*)(lds + o1 + i * 1024);
        }
    };
    auto loadB = [&](int buf, int qc) {
        const int o0 = loB0[buf][qc], o1 = loB1[buf][qc];
#pragma unroll
        for (int j = 0; j < 2; ++j) {
            b[j][0] = *(const short8*)(lds + o0 + j * 1024);
            b[j][1] = *(const short8*)(lds + o1 + j * 1024);
        }
    };
    // swapped operands: D^T -> lane fq*4+r indexes n (cols), fr indexes m (rows)
    auto mma = [&](int qr, int qc) {
#pragma unroll
        for (int i = 0; i < 4; ++i)
#pragma unroll
            for (int j = 0; j < 2; ++j) {
                acc[qr * 4 + i][qc * 2 + j] =
                    __builtin_amdgcn_mfma_f32_16x16x32_bf16(b[j][0], a[i][0], acc[qr * 4 + i][qc * 2 + j], 0, 0, 0);
                acc[qr * 4 + i][qc * 2 + j] =
                    __builtin_amdgcn_mfma_f32_16x16x32_bf16(b[j][1], a[i][1], acc[qr * 4 + i][qc * 2 + j], 0, 0, 0);
            }
    };

#define PRIO1() __builtin_amdgcn_s_setprio(1)
#define BOUT()  __builtin_amdgcn_s_setprio(0); __builtin_amdgcn_s_barrier()
#define VM6()   asm volatile("s_waitcnt vmcnt(6)" ::: "memory")
#define VM0()   asm volatile("s_waitcnt vmcnt(0)" ::: "memory")

    // prologue: stream order per tile = [A0, B1, A1, B0]
    stageA(0, 0, 0);
    stageB(0, 1, 0);
    stageA(0, 1, 0);
    stageB(0, 0, 0);
    stageA(1, 0, 64);
    stageB(1, 1, 64);
    stageA(1, 1, 64);
    VM6();
    __builtin_amdgcn_s_barrier();

    int ko = 0;
    for (int pr = 0; pr < 7; ++pr, ko += 128) {
        // ---- tile t0 (buf0) ----
        loadA(0, 0); loadB(0, 0);
        stageB(1, 0, ko + 64);
        PRIO1(); mma(0, 0); BOUT();

        loadB(0, 1);
        stageA(0, 0, ko + 128);
        PRIO1(); mma(0, 1); BOUT();

        loadA(0, 1);
        stageB(0, 1, ko + 128);
        PRIO1(); mma(1, 1); BOUT();

        loadB(0, 0);
        stageA(0, 1, ko + 128);
        PRIO1(); mma(1, 0); __builtin_amdgcn_s_setprio(0); VM6();
        __builtin_amdgcn_s_barrier();

        // ---- tile t0+1 (buf1) ----
        loadA(1, 0); loadB(1, 0);
        stageB(0, 0, ko + 128);
        PRIO1(); mma(0, 0); BOUT();

        loadB(1, 1);
        stageA(1, 0, ko + 192);
        PRIO1(); mma(0, 1); BOUT();

        loadA(1, 1);
        stageB(1, 1, ko + 192);
        PRIO1(); mma(1, 1); BOUT();

        loadB(1, 0);
        stageA(1, 1, ko + 192);
        PRIO1(); mma(1, 0); __builtin_amdgcn_s_setprio(0); VM6();
        __builtin_amdgcn_s_barrier();
    }

    // peeled last iteration: tiles 14 (buf0), 15 (buf1); ko == 896
    loadA(0, 0); loadB(0, 0);
    stageB(1, 0, 960);
    PRIO1(); mma(0, 0); BOUT();

    loadB(0, 1);
    PRIO1(); mma(0, 1); BOUT();

    loadA(0, 1);
    PRIO1(); mma(1, 1); BOUT();

    loadB(0, 0);
    PRIO1(); mma(1, 0); __builtin_amdgcn_s_setprio(0); VM0();
    __builtin_amdgcn_s_barrier();

    loadA(1, 0); loadB(1, 0);
    PRIO1(); mma(0, 0); BOUT();

    loadB(1, 1);
    PRIO1(); mma(0, 1); BOUT();

    loadA(1, 1);
    PRIO1(); mma(1, 1); BOUT();

    loadB(1, 0);
    PRIO1(); mma(1, 0);
    __builtin_amdgcn_s_setprio(0);

#undef PRIO1
#undef BOUT
#undef VM6
#undef VM0

    // epilogue (swapped layout):
    //   m = m0 + wm_i*128 + (ri>>2)*64 + (ri&3)*16 + fr   (token row)
    //   n = n0 + wn_i*64 + (cj>>1)*32 + (cj&1)*16 + fq*4 + r   (qkv col)
    float4 bv[4];
#pragma unroll
    for (int cj = 0; cj < 4; ++cj) {
        const int nb = n0 + wn_i * 64 + (cj >> 1) * 32 + (cj & 1) * 16 + fq * 4;
        bv[cj] = *(const float4*)&bias[nb];
    }
#pragma unroll
    for (int ri = 0; ri < 8; ++ri) {
        const int m = m0 + wm_i * 128 + (ri >> 2) * 64 + (ri & 3) * 16 + fr;
#pragma unroll
        for (int cj = 0; cj < 4; ++cj) {
            const int col = n0 + wn_i * 64 + (cj >> 1) * 32 + (cj & 1) * 16 + fq * 4;
            if (MODE == 0) {
                const int s = col >> 10;           // 0=q 1=k 2=v (wave-uniform per cj)
                const int c = col & 1023;
                const int h = c >> 6;
                const int d = c & 63;              // aligned 4
                const int bb = m >> 13;
                const int n  = m & 8191;
                float v0 = acc[ri][cj][0] + bv[cj].x;
                float v1 = acc[ri][cj][1] + bv[cj].y;
                float v2 = acc[ri][cj][2] + bv[cj].z;
                float v3 = acc[ri][cj][3] + bv[cj].w;
                if (s < 2) { v0 = elu1(v0); v1 = elu1(v1); v2 = elu1(v2); v3 = elu1(v3); }
                ushort4 o;
                o.x = f2b(v0); o.y = f2b(v1); o.z = f2b(v2); o.w = f2b(v3);
                *(ushort4*)&out_u16[(((size_t)s * 64 + bb * 16 + h) * 8192 + n) * 64 + d] = o;
            } else {
                float4 o;
                o.x = acc[ri][cj][0] + bv[cj].x;
                o.y = acc[ri][cj][1] + bv[cj].y;
                o.z = acc[ri][cj][2] + bv[cj].z;
                o.w = acc[ri][cj][3] + bv[cj].w;
                *(float4*)&out_f32[(size_t)m * Nt + col] = o;
            }
        }
    }
}

// ---------------- kv = k^T v  (+ ksum) per (b,h) ----------------
// kbuf/vbuf: [64][8192][64] bf16 (already elu'd k).  kv: [64][64][64] fp32.  ksum: [64][64].
__global__ __launch_bounds__(256) void kv_kernel(
    const ushort_t* __restrict__ kbuf, const ushort_t* __restrict__ vbuf,
    float* __restrict__ kv, float* __restrict__ ksum)
{
    __shared__ ushort_t ks[64 * 64] __attribute__((aligned(16)));
    __shared__ ushort_t vs[64 * 64] __attribute__((aligned(16)));

    const int bh = blockIdx.y, chunk = blockIdx.x, t = threadIdx.x;
    const int d0 = (t >> 4) * 4, e0 = (t & 15) * 4;
    const bool do_ksum = (t & 15) == 0;

    float acc[4][4];
#pragma unroll
    for (int i = 0; i < 4; ++i)
#pragma unroll
        for (int j = 0; j < 4; ++j) acc[i][j] = 0.f;
    float kacc[4] = {0.f, 0.f, 0.f, 0.f};

    for (int sub = 0; sub < 8; ++sub) {
        const int nb = chunk * 512 + sub * 64;
        __syncthreads();
#pragma unroll
        for (int p = 0; p < 2; ++p) {
            int idx = p * 256 + t;
            int r = idx >> 3, c = (idx & 7) * 8;
            *(short8*)&ks[r * 64 + c] = *(const short8*)&kbuf[((size_t)bh * 8192 + nb + r) * 64 + c];
            *(short8*)&vs[r * 64 + c] = *(const short8*)&vbuf[((size_t)bh * 8192 + nb + r) * 64 + c];
        }
        __syncthreads();
        for (int n = 0; n < 64; ++n) {
            ushort4 kd = *(const ushort4*)&ks[n * 64 + d0];
            ushort4 ve = *(const ushort4*)&vs[n * 64 + e0];
            float kf[4] = {b2f(kd.x), b2f(kd.y), b2f(kd.z), b2f(kd.w)};
            float vf[4] = {b2f(ve.x), b2f(ve.y), b2f(ve.z), b2f(ve.w)};
#pragma unroll
            for (int i = 0; i < 4; ++i) {
#pragma unroll
                for (int j = 0; j < 4; ++j) acc[i][j] += kf[i] * vf[j];
            }
            if (do_ksum) {
#pragma unroll
                for (int i = 0; i < 4; ++i) kacc[i] += kf[i];
            }
        }
    }
#pragma unroll
    for (int i = 0; i < 4; ++i) {
        if (do_ksum) atomicAdd(&ksum[bh * 64 + d0 + i], kacc[i]);
#pragma unroll
        for (int j = 0; j < 4; ++j)
            atomicAdd(&kv[((size_t)bh * 64 + d0 + i) * 64 + e0 + j], acc[i][j]);
    }
}

// ---------------- out = (q @ kv) * z via MFMA, repack to [B][N][C] bf16 ----------------
// D^T[e][n] = sum_d kv[d][e] * q[n][d];  z via A' rows = ksum.
// qbuf: [64][8192][64] bf16 (already elu'd q).  kv fp32 [64][64][64].  ksum fp32.
__global__ __launch_bounds__(256) void out_kernel(
    const ushort_t* __restrict__ qbuf, const float* __restrict__ kv,
    const float* __restrict__ ksum, ushort_t* __restrict__ obuf)
{
    __shared__ float kvs[4096];
    __shared__ float ksums[64];

    const int bh = blockIdx.y, chunk = blockIdx.x, t = threadIdx.x;
    const int b = bh >> 4, h = bh & 15;
    const int wave = t >> 6, lane = t & 63;
    const int tok = lane & 15, fq = lane >> 4;

#pragma unroll
    for (int i = 0; i < 4; ++i) {
        int idx = (i * 256 + t) * 4;
        *(float4*)&kvs[idx] = *(const float4*)&kv[(size_t)bh * 4096 + idx];
    }
    if (t < 64) ksums[t] = ksum[bh * 64 + t];
    __syncthreads();

    // build A'-fragments once: afr[et][ks][i] = kv[d = ks*32+fq*8+i][e = et*16+tok]
    short8 afr[4][2];
#pragma unroll
    for (int et = 0; et < 4; ++et)
#pragma unroll
        for (int kslice = 0; kslice < 2; ++kslice)
#pragma unroll
            for (int i = 0; i < 8; ++i) {
                const int d = kslice * 32 + fq * 8 + i;
                afr[et][kslice][i] = (short)f2b(kvs[d * 64 + et * 16 + tok]);
            }
    short8 zfr[2];
#pragma unroll
    for (int kslice = 0; kslice < 2; ++kslice)
#pragma unroll
        for (int i = 0; i < 8; ++i)
            zfr[kslice][i] = (short)f2b(ksums[kslice * 32 + fq * 8 + i]);

    const floatx4 z4 = {0.f, 0.f, 0.f, 0.f};
    const int nbase = chunk * 1024 + wave * 256;
    const ushort_t* qrow = qbuf + ((size_t)bh * 8192 + nbase + tok) * 64 + fq * 8;
    ushort_t* orow = obuf + ((size_t)b * 8192 + nbase + tok) * 1024 + h * 64 + fq * 4;

#pragma unroll 2
    for (int g = 0; g < 16; ++g) {
        // B'-fragments: q rows, direct from global (16B per lane per slice)
        short8 bf0 = *(const short8*)(qrow + (size_t)g * 16 * 64);
        short8 bf1 = *(const short8*)(qrow + (size_t)g * 16 * 64 + 32);

        floatx4 az = __builtin_amdgcn_mfma_f32_16x16x32_bf16(zfr[0], bf0, z4, 0, 0, 0);
        az = __builtin_amdgcn_mfma_f32_16x16x32_bf16(zfr[1], bf1, az, 0, 0, 0);

        floatx4 ad[4];
#pragma unroll
        for (int et = 0; et < 4; ++et) {
            ad[et] = __builtin_amdgcn_mfma_f32_16x16x32_bf16(afr[et][0], bf0, z4, 0, 0, 0);
            ad[et] = __builtin_amdgcn_mfma_f32_16x16x32_bf16(afr[et][1], bf1, ad[et], 0, 0, 0);
        }

        const float zi = 1.f / (az[0] + 1e-8f);   // every lane holds z for its own token
#pragma unroll
        for (int et = 0; et < 4; ++et) {
            ushort4 o;
            o.x = f2b(ad[et][0] * zi);
            o.y = f2b(ad[et][1] * zi);
            o.z = f2b(ad[et][2] * zi);
            o.w = f2b(ad[et][3] * zi);
            *(ushort4*)&orow[(size_t)g * 16 * 1024 + et * 16] = o;
        }
    }
}

// ---------------- launch ----------------

extern "C" void kernel_launch(void* const* d_in, const int* in_sizes, int n_in,
                              void* d_out, int out_size, void* d_ws, size_t ws_size,
                              hipStream_t stream) {
    const float* x      = (const float*)d_in[0];
    const float* w_qkv  = (const float*)d_in[1];
    const float* b_qkv  = (const float*)d_in[2];
    const float* w_proj = (const float*)d_in[3];
    const float* b_proj = (const float*)d_in[4];
    float* out = (float*)d_out;

    const size_t XE = (size_t)32768 * 1024;

    char* ws = (char*)d_ws;
    ushort_t* xb   = (ushort_t*)ws;  ws += XE * 2;
    ushort_t* wqT  = (ushort_t*)ws;  ws += (size_t)3072 * 1024 * 2;
    ushort_t* wpT  = (ushort_t*)ws;  ws += (size_t)1024 * 1024 * 2;
    ushort_t* qkvb = (ushort_t*)ws;  ws += 3 * XE * 2;   // [3][64][8192][64] scatter
    ushort_t* ob   = (ushort_t*)ws;  ws += XE * 2;       // [32768][1024]
    float*    kv   = (float*)ws;     ws += (size_t)64 * 64 * 64 * 4;
    float*    ksum = (float*)ws;     ws += (size_t)64 * 64 * 4;

    (void)hipFuncSetAttribute(reinterpret_cast<const void*>(gemm256<0>),
                              hipFuncAttributeMaxDynamicSharedMemorySize, 131072);
    (void)hipFuncSetAttribute(reinterpret_cast<const void*>(gemm256<1>),
                              hipFuncAttributeMaxDynamicSharedMemorySize, 131072);

    zero_f32<<<dim3((64 * 64 * 64 + 64 * 64 + 255) / 256), dim3(256), 0, stream>>>(kv, 64 * 64 * 64 + 64 * 64);
    conv_bf16<<<dim3(2048), dim3(256), 0, stream>>>(x, xb, (int)(XE / 8));
    transpose_conv<<<dim3(96, 32), dim3(32, 8), 0, stream>>>(w_qkv, wqT, 1024, 3072);
    transpose_conv<<<dim3(32, 32), dim3(32, 8), 0, stream>>>(w_proj, wpT, 1024, 1024);

    // qkv: M=32768, Nt=3072 -> 12*128 = 1536 blocks
    gemm256<0><<<dim3(1536), dim3(512), 131072, stream>>>(xb, wqT, b_qkv, qkvb, nullptr, 3072, 12);

    kv_kernel<<<dim3(16, 64), dim3(256), 0, stream>>>(qkvb + XE, qkvb + 2 * XE, kv, ksum);
    out_kernel<<<dim3(8, 64), dim3(256), 0, stream>>>(qkvb, kv, ksum, ob);

    // proj: M=32768, Nt=1024 -> 4*128 = 512 blocks
    gemm256<1><<<dim3(512), dim3(512), 131072, stream>>>(ob, wpT, b_proj, nullptr, out, 1024, 4);
}